// Round 6
// baseline (14.004 us; speedup 1.0000x reference)
//
#include <hip/hip_runtime.h>
#include <math.h>

// out[b,c] = sum_n exp(-2*r2(n,b)) * exp(-max(t,0)/2) * mem[n,c]
// Tube-culled: arg = -2*r2 - max(t,0)/2; drop arg < -20 (exp(-20) ~ 2e-9).
// March the dominant axis; per integer plane the relevant cross-section has
// in-plane radius <= 3.17/|d_a| <= 3.17*sqrt(3) ~ 5.5 (+1 rounding) -> a
// 16x16 box centered on the line crossing covers it. Planes with tk > 46
// culled (inside the box t >= tk - 7.5 > 38.5 -> arg < -20).
//
// Structure: memset(2KB) -> single tube kernel; each block finishes with 16
// device-scope atomicAdds into out (no dependent reduce dispatch, no drain
// tail). 1024 blocks x 256 thr, 4 planes/block, wave fold-reduction.
// Measured floor: ~10 us graph-replay/submit overhead; GPU work ~2 us.

constexpr int BRAYS  = 32;
constexpr int DGRID  = 128;
constexpr int NCHUNK = 32;                 // plane-chunks per ray
constexpr int PLANES = DGRID / NCHUNK;     // 4 planes per block
constexpr int NTHR   = 256;
constexpr int NBLK   = BRAYS * NCHUNK;     // 1024 blocks

__global__ __launch_bounds__(NTHR)
void hpm_tube(const float* __restrict__ ray_o,
              const float* __restrict__ ray_d,
              const float* __restrict__ mem,
              float* __restrict__ out)    // [BRAYS][16], pre-zeroed
{
    const int tid   = threadIdx.x;
    const int b     = blockIdx.x & (BRAYS - 1);
    const int chunk = blockIdx.x >> 5;
    const int k0    = chunk * PLANES;

    // ---- ray setup (block-uniform) ----
    const float ox = ray_o[b*3+0], oy = ray_o[b*3+1], oz = ray_o[b*3+2];
    const float dx = ray_d[b*3+0], dy = ray_d[b*3+1], dz = ray_d[b*3+2];
    const float ax = fabsf(dx), ay = fabsf(dy), az = fabsf(dz);

    int a;                                   // dominant axis
    if (ax >= ay && ax >= az) a = 0; else if (ay >= az) a = 1; else a = 2;
    const int p1 = (a == 0) ? 1 : 0;
    const int p2 = (a == 2) ? 1 : 2;

    const float o3[3] = {ox, oy, oz};
    const float d3[3] = {dx, dy, dz};
    const int   st[3] = {DGRID * DGRID * 16, DGRID * 16, 16};  // float strides

    const float oa = o3[a],  da = d3[a];
    const float o1 = o3[p1], d1 = d3[p1];
    const float o2 = o3[p2], d2 = d3[p2];
    const int   sa = st[a],  s1 = st[p1], s2 = st[p2];
    const float inv_da = 1.0f / da;
    const float q = 2.0f - (dx*dx + dy*dy + dz*dz);   // r2 = |e|^2 - q*t^2

    // ---- thread's in-plane box offset ----
    const int u = tid >> 4;    // 0..15 along p1
    const int v = tid & 15;    // 0..15 along p2

    float acc[16];
    #pragma unroll
    for (int c = 0; c < 16; ++c) acc[c] = 0.0f;

    #pragma unroll
    for (int i = 0; i < PLANES; ++i) {
        const int   k  = k0 + i;
        const float tk = ((float)k - oa) * inv_da;     // t at plane crossing
        if (tk > 46.0f) continue;                      // forward decay cull

        const float yc = o1 + tk * d1;
        const float zc = o2 + tk * d2;
        const int y = (int)floorf(yc) - 7 + u;
        const int z = (int)floorf(zc) - 7 + v;

        const float e0 = (float)k - oa;
        const float e1 = (float)y - o1;
        const float e2 = (float)z - o2;
        const float t   = fmaf(e0, da, fmaf(e1, d1, e2 * d2));
        const float ee  = fmaf(e0, e0, fmaf(e1, e1, e2 * e2));
        const float r2  = fmaf(-q * t, t, ee);
        const float arg = fmaf(fmaxf(t, 0.0f), -0.5f, -2.0f * r2);

        if (arg > -20.0f && ((unsigned)y < 128u) && ((unsigned)z < 128u)) {
            const float w = __expf(arg);
            const float4* row = reinterpret_cast<const float4*>(
                mem + (size_t)k * sa + (size_t)y * s1 + (size_t)z * s2);
            const float4 m0 = row[0], m1 = row[1], m2 = row[2], m3 = row[3];
            acc[ 0] = fmaf(w, m0.x, acc[ 0]); acc[ 1] = fmaf(w, m0.y, acc[ 1]);
            acc[ 2] = fmaf(w, m0.z, acc[ 2]); acc[ 3] = fmaf(w, m0.w, acc[ 3]);
            acc[ 4] = fmaf(w, m1.x, acc[ 4]); acc[ 5] = fmaf(w, m1.y, acc[ 5]);
            acc[ 6] = fmaf(w, m1.z, acc[ 6]); acc[ 7] = fmaf(w, m1.w, acc[ 7]);
            acc[ 8] = fmaf(w, m2.x, acc[ 8]); acc[ 9] = fmaf(w, m2.y, acc[ 9]);
            acc[10] = fmaf(w, m2.z, acc[10]); acc[11] = fmaf(w, m2.w, acc[11]);
            acc[12] = fmaf(w, m3.x, acc[12]); acc[13] = fmaf(w, m3.y, acc[13]);
            acc[14] = fmaf(w, m3.z, acc[14]); acc[15] = fmaf(w, m3.w, acc[15]);
        }
    }

    // ---- wave fold-reduction: halve register count each step ----
    // Final: lane<16 holds channel brev4(lane) summed over its 64 lanes.
    const int lane = tid & 63;
    float r[16];
    #pragma unroll
    for (int c = 0; c < 16; ++c) r[c] = acc[c];

#define FOLD(MASK, HALF)                                        \
    {                                                           \
        const bool hi = (lane & (MASK)) != 0;                   \
        _Pragma("unroll")                                       \
        for (int i = 0; i < (HALF); ++i) {                      \
            const float give = hi ? r[i] : r[i + (HALF)];       \
            const float keep = hi ? r[i + (HALF)] : r[i];       \
            r[i] = keep + __shfl_xor(give, (MASK), 64);         \
        }                                                       \
    }
    FOLD(1, 8)
    FOLD(2, 4)
    FOLD(4, 2)
    FOLD(8, 1)
#undef FOLD
    float sum = r[0];
    sum += __shfl_xor(sum, 16, 64);
    sum += __shfl_xor(sum, 32, 64);
    const int l4 = lane & 15;
    const int ch = ((l4 & 1) << 3) | ((l4 & 2) << 1) | ((l4 & 4) >> 1) | ((l4 & 8) >> 3);

    // ---- cross-wave combine (4 waves) + device-scope atomic finish ----
    __shared__ float ws[4][16];
    if (lane < 16) ws[tid >> 6][ch] = sum;
    __syncthreads();

    if (tid < 16) {
        const float p = ws[0][tid] + ws[1][tid] + ws[2][tid] + ws[3][tid];
        atomicAdd(&out[b * 16 + tid], p);
    }
}

extern "C" void kernel_launch(void* const* d_in, const int* in_sizes, int n_in,
                              void* d_out, int out_size, void* d_ws, size_t ws_size,
                              hipStream_t stream)
{
    const float* ray_o = (const float*)d_in[0];   // [32,3]
    const float* ray_d = (const float*)d_in[1];   // [32,3]
    const float* mem   = (const float*)d_in[2];   // [128^3,16]
    float* out = (float*)d_out;                   // [32,16]

    hipMemsetAsync(out, 0, BRAYS * 16 * sizeof(float), stream);
    hipLaunchKernelGGL(hpm_tube, dim3(NBLK), dim3(NTHR), 0, stream,
                       ray_o, ray_d, mem, out);
}

// Round 7
// 11.816 us; speedup vs baseline: 1.1851x; 1.1851x over previous
//
#include <hip/hip_runtime.h>
#include <math.h>

// out[b,c] = sum_n exp(-2*r2(n,b)) * exp(-max(t,0)/2) * mem[n,c]
// Tube-culled: arg = -2*r2 - max(t,0)/2; drop arg < -20 (exp(-20) ~ 2e-9).
// March the dominant axis; per integer plane the relevant cross-section has
// in-plane radius <= 3.17/|d_a| <= 3.17*sqrt(3) ~ 5.5 (+1 rounding) -> a
// 16x16 box centered on the line crossing covers it. Planes with tk > 46
// culled (inside the box t >= tk - 7.5 > 38.5 -> arg < -20).
//
// Structure: SINGLE dispatch, flag fan-in. Blocks 0..1023 = tube producers
// (publish 16 partials + flag via agent-scope atomics); block 1024 = reducer
// (spins on flags, reduces, resets flags to 0 for the next replay — poison
// 0xAAAAAAAA != MAGIC makes the first replay safe, 0 != MAGIC the rest).
// All 1025 blocks co-resident (4 waves x 68 VGPR), no deadlock.

constexpr int BRAYS  = 32;
constexpr int DGRID  = 128;
constexpr int NCHUNK = 32;                 // plane-chunks per ray
constexpr int PLANES = DGRID / NCHUNK;     // 4 planes per block
constexpr int NTHR   = 256;
constexpr int NBLK   = BRAYS * NCHUNK;     // 1024 producer blocks
constexpr unsigned MAGIC = 0x5EEDBEEFu;

#define AT_LOAD(p)     __hip_atomic_load((p), __ATOMIC_RELAXED, __HIP_MEMORY_SCOPE_AGENT)
#define AT_STORE(p, v) __hip_atomic_store((p), (v), __ATOMIC_RELAXED, __HIP_MEMORY_SCOPE_AGENT)

__global__ __launch_bounds__(NTHR)
void hpm_tube(const float* __restrict__ ray_o,
              const float* __restrict__ ray_d,
              const float* __restrict__ mem,
              float* __restrict__ part,      // [NCHUNK][BRAYS][16] in d_ws
              unsigned* __restrict__ flags,  // [NBLK] in d_ws (fan-in only)
              float* __restrict__ out,
              int fanin)
{
    const int tid = threadIdx.x;

    // ---------------- reducer block (fan-in mode only) ----------------
    if (blockIdx.x == NBLK) {
        for (int j = tid; j < NBLK; j += NTHR)
            while (AT_LOAD(&flags[j]) != MAGIC) { /* spin */ }
        __syncthreads();

        for (int e = tid; e < BRAYS * 16; e += NTHR) {
            float s = 0.0f;
            #pragma unroll
            for (int k = 0; k < NCHUNK; ++k)
                s += AT_LOAD(&part[k * (BRAYS * 16) + e]);
            out[e] = s;
        }
        for (int j = tid; j < NBLK; j += NTHR)
            AT_STORE(&flags[j], 0u);
        return;
    }

    // ---------------- producer: tube march ----------------
    const int b     = blockIdx.x & (BRAYS - 1);
    const int chunk = blockIdx.x >> 5;
    const int k0    = chunk * PLANES;

    const float ox = ray_o[b*3+0], oy = ray_o[b*3+1], oz = ray_o[b*3+2];
    const float dx = ray_d[b*3+0], dy = ray_d[b*3+1], dz = ray_d[b*3+2];
    const float ax = fabsf(dx), ay = fabsf(dy), az = fabsf(dz);

    int a;                                   // dominant axis
    if (ax >= ay && ax >= az) a = 0; else if (ay >= az) a = 1; else a = 2;
    const int p1 = (a == 0) ? 1 : 0;
    const int p2 = (a == 2) ? 1 : 2;

    const float o3[3] = {ox, oy, oz};
    const float d3[3] = {dx, dy, dz};
    const int   st[3] = {DGRID * DGRID * 16, DGRID * 16, 16};  // float strides

    const float oa = o3[a],  da = d3[a];
    const float o1 = o3[p1], d1 = d3[p1];
    const float o2 = o3[p2], d2 = d3[p2];
    const int   sa = st[a],  s1 = st[p1], s2 = st[p2];
    const float inv_da = 1.0f / da;
    const float q = 2.0f - (dx*dx + dy*dy + dz*dz);   // r2 = |e|^2 - q*t^2

    const int u = tid >> 4;    // 0..15 along p1
    const int v = tid & 15;    // 0..15 along p2

    float acc[16];
    #pragma unroll
    for (int c = 0; c < 16; ++c) acc[c] = 0.0f;

    #pragma unroll
    for (int i = 0; i < PLANES; ++i) {
        const int   k  = k0 + i;
        const float tk = ((float)k - oa) * inv_da;     // t at plane crossing
        if (tk > 46.0f) continue;                      // forward decay cull

        const float yc = o1 + tk * d1;
        const float zc = o2 + tk * d2;
        const int y = (int)floorf(yc) - 7 + u;
        const int z = (int)floorf(zc) - 7 + v;

        const float e0 = (float)k - oa;
        const float e1 = (float)y - o1;
        const float e2 = (float)z - o2;
        const float t   = fmaf(e0, da, fmaf(e1, d1, e2 * d2));
        const float ee  = fmaf(e0, e0, fmaf(e1, e1, e2 * e2));
        const float r2  = fmaf(-q * t, t, ee);
        const float arg = fmaf(fmaxf(t, 0.0f), -0.5f, -2.0f * r2);

        if (arg > -20.0f && ((unsigned)y < 128u) && ((unsigned)z < 128u)) {
            const float w = __expf(arg);
            const float4* row = reinterpret_cast<const float4*>(
                mem + (size_t)k * sa + (size_t)y * s1 + (size_t)z * s2);
            const float4 m0 = row[0], m1 = row[1], m2 = row[2], m3 = row[3];
            acc[ 0] = fmaf(w, m0.x, acc[ 0]); acc[ 1] = fmaf(w, m0.y, acc[ 1]);
            acc[ 2] = fmaf(w, m0.z, acc[ 2]); acc[ 3] = fmaf(w, m0.w, acc[ 3]);
            acc[ 4] = fmaf(w, m1.x, acc[ 4]); acc[ 5] = fmaf(w, m1.y, acc[ 5]);
            acc[ 6] = fmaf(w, m1.z, acc[ 6]); acc[ 7] = fmaf(w, m1.w, acc[ 7]);
            acc[ 8] = fmaf(w, m2.x, acc[ 8]); acc[ 9] = fmaf(w, m2.y, acc[ 9]);
            acc[10] = fmaf(w, m2.z, acc[10]); acc[11] = fmaf(w, m2.w, acc[11]);
            acc[12] = fmaf(w, m3.x, acc[12]); acc[13] = fmaf(w, m3.y, acc[13]);
            acc[14] = fmaf(w, m3.z, acc[14]); acc[15] = fmaf(w, m3.w, acc[15]);
        }
    }

    // ---- wave fold-reduction (register-halving shuffles) ----
    const int lane = tid & 63;
    float r[16];
    #pragma unroll
    for (int c = 0; c < 16; ++c) r[c] = acc[c];

#define FOLD(MASK, HALF)                                        \
    {                                                           \
        const bool hi = (lane & (MASK)) != 0;                   \
        _Pragma("unroll")                                       \
        for (int i = 0; i < (HALF); ++i) {                      \
            const float give = hi ? r[i] : r[i + (HALF)];       \
            const float keep = hi ? r[i + (HALF)] : r[i];       \
            r[i] = keep + __shfl_xor(give, (MASK), 64);         \
        }                                                       \
    }
    FOLD(1, 8)
    FOLD(2, 4)
    FOLD(4, 2)
    FOLD(8, 1)
#undef FOLD
    float sum = r[0];
    sum += __shfl_xor(sum, 16, 64);
    sum += __shfl_xor(sum, 32, 64);
    const int l4 = lane & 15;
    const int ch = ((l4 & 1) << 3) | ((l4 & 2) << 1) | ((l4 & 4) >> 1) | ((l4 & 8) >> 3);

    // ---- cross-wave combine (4 waves) + publish ----
    __shared__ float ws[4][16];
    if (lane < 16) ws[tid >> 6][ch] = sum;
    __syncthreads();

    if (tid < 16) {
        const float p = ws[0][tid] + ws[1][tid] + ws[2][tid] + ws[3][tid];
        AT_STORE(&part[(chunk * BRAYS + b) * 16 + tid], p);
    }

    if (fanin) {
        // __syncthreads emits s_waitcnt vmcnt(0) before s_barrier -> the
        // agent-scope partial stores are at the coherence point before the
        // flag becomes visible.
        __syncthreads();
        if (tid == 0) AT_STORE(&flags[chunk * BRAYS + b], MAGIC);
    }
}

// Fallback tail reduce (only if ws_size can't hold the flags).
__global__ __launch_bounds__(512)
void hpm_reduce(const float* __restrict__ part, float* __restrict__ out)
{
    const int e = threadIdx.x;
    float s = 0.0f;
    #pragma unroll
    for (int k = 0; k < NCHUNK; ++k)
        s += part[k * (BRAYS * 16) + e];
    out[e] = s;
}

extern "C" void kernel_launch(void* const* d_in, const int* in_sizes, int n_in,
                              void* d_out, int out_size, void* d_ws, size_t ws_size,
                              hipStream_t stream)
{
    const float* ray_o = (const float*)d_in[0];   // [32,3]
    const float* ray_d = (const float*)d_in[1];   // [32,3]
    const float* mem   = (const float*)d_in[2];   // [128^3,16]
    float* out  = (float*)d_out;                  // [32,16]

    float*    part  = (float*)d_ws;                            // 64 KB
    unsigned* flags = (unsigned*)((char*)d_ws + NBLK * 64);    // +4 KB

    const size_t need = (size_t)NBLK * 64 + NBLK * sizeof(unsigned);
    const int fanin = (ws_size >= need) ? 1 : 0;

    if (fanin) {
        hipLaunchKernelGGL(hpm_tube, dim3(NBLK + 1), dim3(NTHR), 0, stream,
                           ray_o, ray_d, mem, part, flags, out, 1);
    } else {
        hipLaunchKernelGGL(hpm_tube, dim3(NBLK), dim3(NTHR), 0, stream,
                           ray_o, ray_d, mem, part, flags, out, 0);
        hipLaunchKernelGGL(hpm_reduce, dim3(1), dim3(512), 0, stream,
                           part, out);
    }
}